// Round 1
// baseline (4116.673 us; speedup 1.0000x reference)
//
#include <hip/hip_runtime.h>
#include <hip/hip_bf16.h>
#include <math.h>

#define N_NODES 50000
#define N_EDGES 800000
#define E_TOT   (N_EDGES + N_NODES)
#define N_GRAPHS 256
#define SLOPE 0.2f

// ---------------- GEMM: C[M,N] = A[M,K] @ W[K,N] + bias ----------------
// 64x64 tile, BK=16, 256 threads, 4x4 per thread.
__global__ __launch_bounds__(256) void gemm_bias(
    const float* __restrict__ A, const float* __restrict__ W,
    const float* __restrict__ bias, float* __restrict__ C,
    int M, int K, int N) {
  __shared__ float As[64][17];
  __shared__ float Bs[16][64];
  const int tid = threadIdx.x;
  const int bm = blockIdx.x, bn = blockIdx.y;
  const int row0 = bm * 64, col0 = bn * 64;
  const int tx = tid & 15, ty = tid >> 4;
  float acc[4][4] = {};
  for (int k0 = 0; k0 < K; k0 += 16) {
#pragma unroll
    for (int i = 0; i < 4; ++i) {
      int idx = tid + i * 256;
      int r = idx >> 4, c = idx & 15;
      int gr = row0 + r, gc = k0 + c;
      As[r][c] = (gr < M && gc < K) ? A[(size_t)gr * K + gc] : 0.f;
    }
#pragma unroll
    for (int i = 0; i < 4; ++i) {
      int idx = tid + i * 256;
      int r = idx >> 6, c = idx & 63;
      int gr = k0 + r, gc = col0 + c;
      Bs[r][c] = (gr < K && gc < N) ? W[(size_t)gr * N + gc] : 0.f;
    }
    __syncthreads();
#pragma unroll
    for (int kk = 0; kk < 16; ++kk) {
      float a[4], b[4];
#pragma unroll
      for (int i = 0; i < 4; ++i) a[i] = As[ty * 4 + i][kk];
#pragma unroll
      for (int j = 0; j < 4; ++j) b[j] = Bs[kk][tx * 4 + j];
#pragma unroll
      for (int i = 0; i < 4; ++i)
#pragma unroll
        for (int j = 0; j < 4; ++j) acc[i][j] += a[i] * b[j];
    }
    __syncthreads();
  }
#pragma unroll
  for (int i = 0; i < 4; ++i) {
    int gr = row0 + ty * 4 + i;
    if (gr >= M) continue;
#pragma unroll
    for (int j = 0; j < 4; ++j) {
      int gc = col0 + tx * 4 + j;
      if (gc < N) C[(size_t)gr * N + gc] = acc[i][j] + bias[gc];
    }
  }
}

// ---------------- per-layer init: zero h accum, mx=-inf, denom=0 --------
__global__ void init_layer(float* __restrict__ h, float* __restrict__ mx,
                           float* __restrict__ denom, int nh) {
  int i = blockIdx.x * blockDim.x + threadIdx.x;
  if (i < nh) h[i] = 0.f;
  if (i < N_NODES) { mx[i] = -INFINITY; denom[i] = 0.f; }
}

// ------------- edge logits + segment max (wave per edge) ----------------
__global__ void edge_logit_max(const int* __restrict__ ei,
                               const float* __restrict__ xl,
                               const float* __restrict__ xr,
                               const float* __restrict__ att,
                               float* __restrict__ logit,
                               float* __restrict__ mx, int C) {
  int e = (int)((blockIdx.x * (size_t)blockDim.x + threadIdx.x) >> 6);
  int lane = threadIdx.x & 63;
  if (e >= E_TOT) return;
  int s, d;
  if (e < N_EDGES) { s = ei[e]; d = ei[N_EDGES + e]; }
  else             { s = d = e - N_EDGES; }
  const float* pl = xl + (size_t)s * C;
  const float* pr = xr + (size_t)d * C;
  float v = 0.f;
  for (int c = lane; c < C; c += 64) {
    float m = pl[c] + pr[c];
    float lr = m > 0.f ? m : SLOPE * m;
    v += lr * att[c];
  }
#pragma unroll
  for (int off = 32; off > 0; off >>= 1) v += __shfl_down(v, off, 64);
  if (lane == 0) {
    logit[e] = v;
    if (v >= 0.f) atomicMax((int*)&mx[d], __float_as_int(v));
    else          atomicMin((unsigned int*)&mx[d], __float_as_uint(v));
  }
}

// ------------- exp(logit - mx[dst]) and segment sum ---------------------
__global__ void edge_exp_sum(const int* __restrict__ ei,
                             float* __restrict__ logit,
                             const float* __restrict__ mx,
                             float* __restrict__ denom) {
  int e = blockIdx.x * blockDim.x + threadIdx.x;
  if (e >= E_TOT) return;
  int d = (e < N_EDGES) ? ei[N_EDGES + e] : e - N_EDGES;
  float a = expf(logit[e] - mx[d]);
  logit[e] = a;
  atomicAdd(&denom[d], a);
}

// ------------- out[dst] += alpha * xl[src] (wave per edge) --------------
__global__ void edge_scatter(const int* __restrict__ ei,
                             const float* __restrict__ anum,
                             const float* __restrict__ denom,
                             const float* __restrict__ xl,
                             float* __restrict__ hout, int C) {
  int e = (int)((blockIdx.x * (size_t)blockDim.x + threadIdx.x) >> 6);
  int lane = threadIdx.x & 63;
  if (e >= E_TOT) return;
  int s, d;
  if (e < N_EDGES) { s = ei[e]; d = ei[N_EDGES + e]; }
  else             { s = d = e - N_EDGES; }
  float alpha = anum[e] / denom[d];
  const float* pl = xl + (size_t)s * C;
  float* po = hout + (size_t)d * C;
  for (int c = lane; c < C; c += 64) {
    atomicAdd(&po[c], alpha * pl[c]);
  }
}

// ------------- bias + relu ----------------------------------------------
__global__ void bias_relu(float* __restrict__ h, const float* __restrict__ bias,
                          int nh, int C) {
  int i = blockIdx.x * blockDim.x + threadIdx.x;
  if (i >= nh) return;
  float v = h[i] + bias[i % C];
  h[i] = v > 0.f ? v : 0.f;
}

// ------------- global mean pool (batch sorted) --------------------------
__device__ int lower_bound_dev(const int* a, int n, int v) {
  int lo = 0, hi = n;
  while (lo < hi) { int mid = (lo + hi) >> 1; if (a[mid] < v) lo = mid + 1; else hi = mid; }
  return lo;
}

__global__ void pool_mean(const float* __restrict__ h, const int* __restrict__ batch,
                          float* __restrict__ g, int C) {
  int gi = blockIdx.x;
  int start = lower_bound_dev(batch, N_NODES, gi);
  int end   = lower_bound_dev(batch, N_NODES, gi + 1);
  int cnt = end - start;
  float inv = 1.f / (float)(cnt > 0 ? cnt : 1);
  for (int c = threadIdx.x; c < C; c += blockDim.x) {
    float s = 0.f;
    for (int n = start; n < end; ++n) s += h[(size_t)n * C + c];
    g[(size_t)gi * C + c] = s * inv;
  }
}

// ------------- small per-graph FC: out[g,:] = act(row @ W + b) ----------
__global__ void fc_kernel(const float* __restrict__ g, const float* __restrict__ W,
                          const float* __restrict__ b, float* __restrict__ out,
                          int K, int N, int do_relu) {
  __shared__ float row[304];
  int gi = blockIdx.x;
  for (int k = threadIdx.x; k < K; k += blockDim.x) row[k] = g[(size_t)gi * K + k];
  __syncthreads();
  int c = threadIdx.x;
  if (c >= N) return;
  float s = b[c];
  for (int k = 0; k < K; ++k) s += row[k] * W[(size_t)k * N + c];
  if (do_relu) s = fmaxf(s, 0.f);
  out[(size_t)gi * N + c] = s;
}

extern "C" void kernel_launch(void* const* d_in, const int* in_sizes, int n_in,
                              void* d_out, int out_size, void* d_ws, size_t ws_size,
                              hipStream_t stream) {
  const float* x     = (const float*)d_in[0];
  const int*   ei    = (const int*)d_in[1];
  const int*   batch = (const int*)d_in[2];
  const float* Wl[4], *bl[4], *Wr[4], *br[4], *att[4], *bias[4];
  for (int l = 0; l < 4; ++l) {
    Wl[l]   = (const float*)d_in[3 + l * 6 + 0];
    bl[l]   = (const float*)d_in[3 + l * 6 + 1];
    Wr[l]   = (const float*)d_in[3 + l * 6 + 2];
    br[l]   = (const float*)d_in[3 + l * 6 + 3];
    att[l]  = (const float*)d_in[3 + l * 6 + 4];
    bias[l] = (const float*)d_in[3 + l * 6 + 5];
  }
  const float* fc1_W = (const float*)d_in[27];
  const float* fc1_b = (const float*)d_in[28];
  const float* fc2_W = (const float*)d_in[29];
  const float* fc2_b = (const float*)d_in[30];

  float* ws = (float*)d_ws;
  size_t off = 0;
  float* hbuf  = ws + off; off += (size_t)N_NODES * 300;
  float* xl    = ws + off; off += (size_t)N_NODES * 300;
  float* xr    = ws + off; off += (size_t)N_NODES * 300;
  float* elog  = ws + off; off += E_TOT;
  float* mx    = ws + off; off += N_NODES;
  float* denom = ws + off; off += N_NODES;
  float* gpool = ws + off; off += (size_t)N_GRAPHS * 300;
  float* g1    = ws + off; off += (size_t)N_GRAPHS * 300;

  const int dims[5] = {300, 128, 128, 128, 300};
  const float* hin = x;
  for (int l = 0; l < 4; ++l) {
    int K = dims[l], C = dims[l + 1];
    dim3 gg((N_NODES + 63) / 64, (C + 63) / 64);
    gemm_bias<<<gg, 256, 0, stream>>>(hin, Wl[l], bl[l], xl, N_NODES, K, C);
    gemm_bias<<<gg, 256, 0, stream>>>(hin, Wr[l], br[l], xr, N_NODES, K, C);
    int nh = N_NODES * C;
    init_layer<<<(nh + 255) / 256, 256, 0, stream>>>(hbuf, mx, denom, nh);
    {
      size_t th = (size_t)E_TOT * 64;
      edge_logit_max<<<(unsigned)((th + 255) / 256), 256, 0, stream>>>(ei, xl, xr, att[l], elog, mx, C);
    }
    edge_exp_sum<<<(E_TOT + 255) / 256, 256, 0, stream>>>(ei, elog, mx, denom);
    {
      size_t th = (size_t)E_TOT * 64;
      edge_scatter<<<(unsigned)((th + 255) / 256), 256, 0, stream>>>(ei, elog, denom, xl, hbuf, C);
    }
    bias_relu<<<(nh + 255) / 256, 256, 0, stream>>>(hbuf, bias[l], nh, C);
    hin = hbuf;
  }
  pool_mean<<<N_GRAPHS, 256, 0, stream>>>(hbuf, batch, gpool, 300);
  fc_kernel<<<N_GRAPHS, 320, 0, stream>>>(gpool, fc1_W, fc1_b, g1, 300, 300, 1);
  fc_kernel<<<N_GRAPHS, 768, 0, stream>>>(g1, fc2_W, fc2_b, (float*)d_out, 300, 768, 0);
}

// Round 2
// 1427.532 us; speedup vs baseline: 2.8838x; 2.8838x over previous
//
#include <hip/hip_runtime.h>
#include <hip/hip_bf16.h>
#include <math.h>

#define N_NODES 50000
#define N_EDGES 800000
#define E_TOT   (N_EDGES + N_NODES)
#define N_GRAPHS 256
#define SLOPE 0.2f
#define NB_SCAN ((N_NODES + 255) / 256)   // 196 blocks of 256

// ---------------- GEMM: C[M,N] = A[M,K] @ W[K,N] + bias ----------------
__global__ __launch_bounds__(256) void gemm_bias(
    const float* __restrict__ A, const float* __restrict__ W,
    const float* __restrict__ bias, float* __restrict__ C,
    int M, int K, int N) {
  __shared__ float As[64][17];
  __shared__ float Bs[16][64];
  const int tid = threadIdx.x;
  const int bm = blockIdx.x, bn = blockIdx.y;
  const int row0 = bm * 64, col0 = bn * 64;
  const int tx = tid & 15, ty = tid >> 4;
  float acc[4][4] = {};
  for (int k0 = 0; k0 < K; k0 += 16) {
#pragma unroll
    for (int i = 0; i < 4; ++i) {
      int idx = tid + i * 256;
      int r = idx >> 4, c = idx & 15;
      int gr = row0 + r, gc = k0 + c;
      As[r][c] = (gr < M && gc < K) ? A[(size_t)gr * K + gc] : 0.f;
    }
#pragma unroll
    for (int i = 0; i < 4; ++i) {
      int idx = tid + i * 256;
      int r = idx >> 6, c = idx & 63;
      int gr = k0 + r, gc = col0 + c;
      Bs[r][c] = (gr < K && gc < N) ? W[(size_t)gr * N + gc] : 0.f;
    }
    __syncthreads();
#pragma unroll
    for (int kk = 0; kk < 16; ++kk) {
      float a[4], b[4];
#pragma unroll
      for (int i = 0; i < 4; ++i) a[i] = As[ty * 4 + i][kk];
#pragma unroll
      for (int j = 0; j < 4; ++j) b[j] = Bs[kk][tx * 4 + j];
#pragma unroll
      for (int i = 0; i < 4; ++i)
#pragma unroll
        for (int j = 0; j < 4; ++j) acc[i][j] += a[i] * b[j];
    }
    __syncthreads();
  }
#pragma unroll
  for (int i = 0; i < 4; ++i) {
    int gr = row0 + ty * 4 + i;
    if (gr >= M) continue;
#pragma unroll
    for (int j = 0; j < 4; ++j) {
      int gc = col0 + tx * 4 + j;
      if (gc < N) C[(size_t)gr * N + gc] = acc[i][j] + bias[gc];
    }
  }
}

// ---------------- CSR build (once per launch) ---------------------------
__global__ void zero_ints(int* __restrict__ p, int n) {
  int i = blockIdx.x * blockDim.x + threadIdx.x;
  if (i < n) p[i] = 0;
}

__global__ void deg_count(const int* __restrict__ ei, int* __restrict__ deg) {
  int e = blockIdx.x * blockDim.x + threadIdx.x;
  if (e >= E_TOT) return;
  int d = (e < N_EDGES) ? ei[N_EDGES + e] : e - N_EDGES;
  atomicAdd(&deg[d], 1);
}

__global__ void scan1(const int* __restrict__ deg, int* __restrict__ rp,
                      int* __restrict__ bsum) {
  __shared__ int s[256];
  int i = blockIdx.x * 256 + threadIdx.x;
  int v = (i < N_NODES) ? deg[i] : 0;
  s[threadIdx.x] = v;
  __syncthreads();
  for (int off = 1; off < 256; off <<= 1) {
    int t = (threadIdx.x >= off) ? s[threadIdx.x - off] : 0;
    __syncthreads();
    s[threadIdx.x] += t;
    __syncthreads();
  }
  if (i < N_NODES) rp[i] = s[threadIdx.x] - v;      // block-local exclusive
  if (threadIdx.x == 255) bsum[blockIdx.x] = s[255];
}

__global__ void scan2(int* __restrict__ bsum) {       // one block, 256 >= NB_SCAN
  __shared__ int s[256];
  int v = (threadIdx.x < NB_SCAN) ? bsum[threadIdx.x] : 0;
  s[threadIdx.x] = v;
  __syncthreads();
  for (int off = 1; off < 256; off <<= 1) {
    int t = (threadIdx.x >= off) ? s[threadIdx.x - off] : 0;
    __syncthreads();
    s[threadIdx.x] += t;
    __syncthreads();
  }
  if (threadIdx.x < NB_SCAN) bsum[threadIdx.x] = s[threadIdx.x] - v;  // exclusive
}

__global__ void scan3(int* __restrict__ rp, const int* __restrict__ bsum,
                      int* __restrict__ cursor) {
  int i = blockIdx.x * 256 + threadIdx.x;
  if (i < N_NODES) {
    int v = rp[i] + bsum[blockIdx.x];
    rp[i] = v;
    cursor[i] = v;
  }
  if (i == 0) rp[N_NODES] = E_TOT;
}

__global__ void fill_csr(const int* __restrict__ ei, int* __restrict__ cursor,
                         int* __restrict__ csr_src) {
  int e = blockIdx.x * blockDim.x + threadIdx.x;
  if (e >= E_TOT) return;
  int s, d;
  if (e < N_EDGES) { s = ei[e]; d = ei[N_EDGES + e]; }
  else             { s = d = e - N_EDGES; }
  int pos = atomicAdd(&cursor[d], 1);
  csr_src[pos] = s;
}

// -------- fused GATv2 aggregation: wave per dst node, online softmax ----
template <int C>
__global__ __launch_bounds__(256) void gat_fused(
    const int* __restrict__ rowptr, const int* __restrict__ csr_src,
    const float* __restrict__ xl, const float* __restrict__ xr,
    const float* __restrict__ att, const float* __restrict__ bias,
    float* __restrict__ hout) {
  constexpr int NC = (C + 63) / 64;
  int wid = (int)((blockIdx.x * (size_t)blockDim.x + threadIdx.x) >> 6);
  int lane = threadIdx.x & 63;
  if (wid >= N_NODES) return;
  int beg = rowptr[wid], end = rowptr[wid + 1];

  float xri[NC], attc[NC], acc[NC];
#pragma unroll
  for (int j = 0; j < NC; ++j) {
    int c = lane + j * 64;
    bool ok = (c < C);
    xri[j] = ok ? xr[(size_t)wid * C + c] : 0.f;
    attc[j] = ok ? att[c] : 0.f;
    acc[j] = 0.f;
  }
  float mx = -INFINITY, denom = 0.f;
  for (int e = beg; e < end; ++e) {
    int s = csr_src[e];
    float xlv[NC];
    float v = 0.f;
#pragma unroll
    for (int j = 0; j < NC; ++j) {
      int c = lane + j * 64;
      xlv[j] = (c < C) ? xl[(size_t)s * C + c] : 0.f;
      float m = xlv[j] + xri[j];
      float lr = m > 0.f ? m : SLOPE * m;
      v += lr * attc[j];
    }
#pragma unroll
    for (int off = 1; off < 64; off <<= 1) v += __shfl_xor(v, off, 64);
    float nm = fmaxf(mx, v);
    float scale = expf(mx - nm);   // 0 on first edge (mx=-inf)
    float w = expf(v - nm);
    denom = denom * scale + w;
#pragma unroll
    for (int j = 0; j < NC; ++j) acc[j] = acc[j] * scale + w * xlv[j];
    mx = nm;
  }
  float inv = 1.f / denom;
#pragma unroll
  for (int j = 0; j < NC; ++j) {
    int c = lane + j * 64;
    if (c < C) {
      float v = acc[j] * inv + bias[c];
      hout[(size_t)wid * C + c] = fmaxf(v, 0.f);   // relu after every layer
    }
  }
}

// ------------- global mean pool (batch sorted) --------------------------
__device__ int lower_bound_dev(const int* a, int n, int v) {
  int lo = 0, hi = n;
  while (lo < hi) { int mid = (lo + hi) >> 1; if (a[mid] < v) lo = mid + 1; else hi = mid; }
  return lo;
}

__global__ void pool_mean(const float* __restrict__ h, const int* __restrict__ batch,
                          float* __restrict__ g, int C) {
  int gi = blockIdx.x;
  int start = lower_bound_dev(batch, N_NODES, gi);
  int end   = lower_bound_dev(batch, N_NODES, gi + 1);
  int cnt = end - start;
  float inv = 1.f / (float)(cnt > 0 ? cnt : 1);
  for (int c = threadIdx.x; c < C; c += blockDim.x) {
    float s = 0.f;
    for (int n = start; n < end; ++n) s += h[(size_t)n * C + c];
    g[(size_t)gi * C + c] = s * inv;
  }
}

// ------------- small per-graph FC ---------------------------------------
__global__ void fc_kernel(const float* __restrict__ g, const float* __restrict__ W,
                          const float* __restrict__ b, float* __restrict__ out,
                          int K, int N, int do_relu) {
  __shared__ float row[304];
  int gi = blockIdx.x;
  for (int k = threadIdx.x; k < K; k += blockDim.x) row[k] = g[(size_t)gi * K + k];
  __syncthreads();
  int c = threadIdx.x;
  if (c >= N) return;
  float s = b[c];
  for (int k = 0; k < K; ++k) s += row[k] * W[(size_t)k * N + c];
  if (do_relu) s = fmaxf(s, 0.f);
  out[(size_t)gi * N + c] = s;
}

extern "C" void kernel_launch(void* const* d_in, const int* in_sizes, int n_in,
                              void* d_out, int out_size, void* d_ws, size_t ws_size,
                              hipStream_t stream) {
  const float* x     = (const float*)d_in[0];
  const int*   ei    = (const int*)d_in[1];
  const int*   batch = (const int*)d_in[2];
  const float* Wl[4], *bl[4], *Wr[4], *br[4], *att[4], *bias[4];
  for (int l = 0; l < 4; ++l) {
    Wl[l]   = (const float*)d_in[3 + l * 6 + 0];
    bl[l]   = (const float*)d_in[3 + l * 6 + 1];
    Wr[l]   = (const float*)d_in[3 + l * 6 + 2];
    br[l]   = (const float*)d_in[3 + l * 6 + 3];
    att[l]  = (const float*)d_in[3 + l * 6 + 4];
    bias[l] = (const float*)d_in[3 + l * 6 + 5];
  }
  const float* fc1_W = (const float*)d_in[27];
  const float* fc1_b = (const float*)d_in[28];
  const float* fc2_W = (const float*)d_in[29];
  const float* fc2_b = (const float*)d_in[30];

  char* wsb = (char*)d_ws;
  size_t off = 0;
  auto alloc_f = [&](size_t n) { float* p = (float*)(wsb + off); off += n * 4; return p; };
  auto alloc_i = [&](size_t n) { int* p = (int*)(wsb + off); off += n * 4; return p; };

  float* hbuf  = alloc_f((size_t)N_NODES * 300);
  float* xl    = alloc_f((size_t)N_NODES * 300);
  float* xr    = alloc_f((size_t)N_NODES * 300);
  float* gpool = alloc_f((size_t)N_GRAPHS * 300);
  float* g1    = alloc_f((size_t)N_GRAPHS * 300);
  int*   deg     = alloc_i(N_NODES);
  int*   rowptr  = alloc_i(N_NODES + 1);
  int*   bsum    = alloc_i(256);
  int*   cursor  = alloc_i(N_NODES);
  int*   csr_src = alloc_i(E_TOT);

  // ---- build CSR once (edges are layer-invariant) ----
  zero_ints<<<(N_NODES + 255) / 256, 256, 0, stream>>>(deg, N_NODES);
  deg_count<<<(E_TOT + 255) / 256, 256, 0, stream>>>(ei, deg);
  scan1<<<NB_SCAN, 256, 0, stream>>>(deg, rowptr, bsum);
  scan2<<<1, 256, 0, stream>>>(bsum);
  scan3<<<NB_SCAN, 256, 0, stream>>>(rowptr, bsum, cursor);
  fill_csr<<<(E_TOT + 255) / 256, 256, 0, stream>>>(ei, cursor, csr_src);

  const int dims[5] = {300, 128, 128, 128, 300};
  const float* hin = x;
  const int nwave_blocks = (N_NODES + 3) / 4;   // 4 waves (nodes) per 256-thread block
  for (int l = 0; l < 4; ++l) {
    int K = dims[l], C = dims[l + 1];
    dim3 gg((N_NODES + 63) / 64, (C + 63) / 64);
    gemm_bias<<<gg, 256, 0, stream>>>(hin, Wl[l], bl[l], xl, N_NODES, K, C);
    gemm_bias<<<gg, 256, 0, stream>>>(hin, Wr[l], br[l], xr, N_NODES, K, C);
    if (C == 128) {
      gat_fused<128><<<nwave_blocks, 256, 0, stream>>>(rowptr, csr_src, xl, xr, att[l], bias[l], hbuf);
    } else {
      gat_fused<300><<<nwave_blocks, 256, 0, stream>>>(rowptr, csr_src, xl, xr, att[l], bias[l], hbuf);
    }
    hin = hbuf;
  }
  pool_mean<<<N_GRAPHS, 256, 0, stream>>>(hbuf, batch, gpool, 300);
  fc_kernel<<<N_GRAPHS, 320, 0, stream>>>(gpool, fc1_W, fc1_b, g1, 300, 300, 1);
  fc_kernel<<<N_GRAPHS, 768, 0, stream>>>(g1, fc2_W, fc2_b, (float*)d_out, 300, 768, 0);
}

// Round 4
// 1021.156 us; speedup vs baseline: 4.0314x; 1.3980x over previous
//
#include <hip/hip_runtime.h>
#include <hip/hip_bf16.h>
#include <math.h>

#define N_NODES 50000
#define N_EDGES 800000
#define E_TOT   (N_EDGES + N_NODES)
#define N_GRAPHS 256
#define SLOPE 0.2f
#define NB_SCAN ((N_NODES + 255) / 256)
#define NPANEL 782            // ceil(50000/64)
#define WCOLS 768             // padded concatenated-W width

typedef __attribute__((ext_vector_type(8))) short s16x8;
typedef __attribute__((ext_vector_type(4))) float f32x4;
typedef unsigned short u16;

__device__ __forceinline__ u16 f2bf(float v) {
  unsigned u = __float_as_uint(v);
  unsigned r = (u + 0x7fffu + ((u >> 16) & 1u)) >> 16;
  return (u16)r;
}
__device__ __forceinline__ float bf2f(u16 b) {
  return __uint_as_float(((unsigned)b) << 16);
}

__device__ __forceinline__ void gl_lds16(const void* g, void* l) {
  __builtin_amdgcn_global_load_lds(
      (const __attribute__((address_space(1))) unsigned int*)g,
      (__attribute__((address_space(3))) unsigned int*)l, 16, 0, 0);
}

// ---- x -> panel-swizzled split-bf16 [p][kc=40][m=64][ki=8], zero-padded ----
__global__ void conv_x(const float* __restrict__ x, u16* __restrict__ Ah,
                       u16* __restrict__ Al) {
  int id = blockIdx.x * blockDim.x + threadIdx.x;
  const int total = NPANEL * 64 * 40;
  if (id >= total) return;
  int kc = id % 40;
  int m  = (id / 40) % 64;
  int p  = id / 2560;
  int n = p * 64 + m;
  s16x8 hv, lv;
#pragma unroll
  for (int i = 0; i < 8; ++i) {
    int k = kc * 8 + i;
    float v = (n < N_NODES && k < 300) ? x[(size_t)n * 300 + k] : 0.f;
    u16 hb = f2bf(v);
    hv[i] = (short)hb;
    lv[i] = (short)f2bf(v - bf2f(hb));
  }
  size_t ce = (((size_t)p * 40 + kc) * 64 + m) * 8;
  *(s16x8*)&Ah[ce] = hv;
  *(s16x8*)&Al[ce] = lv;
}

// ---- Wl,Wr -> concatenated padded split-bf16 [kc][WCOLS][8] ----------------
__global__ void conv_w(const float* __restrict__ Wl, const float* __restrict__ Wr,
                       u16* __restrict__ Wh, u16* __restrict__ Wlo,
                       int K, int C, int NL, int kcn) {
  int id = blockIdx.x * blockDim.x + threadIdx.x;
  if (id >= kcn * WCOLS) return;
  int n = id % WCOLS, kc = id / WCOLS;
  s16x8 hv, lv;
#pragma unroll
  for (int i = 0; i < 8; ++i) {
    int k = kc * 8 + i;
    float v = 0.f;
    if (k < K) {
      if (n < NL) { if (n < C) v = Wl[(size_t)k * C + n]; }
      else if (n < 2 * NL && (n - NL) < C) v = Wr[(size_t)k * C + (n - NL)];
    }
    u16 hb = f2bf(v);
    hv[i] = (short)hb;
    lv[i] = (short)f2bf(v - bf2f(hb));
  }
  size_t ce = (size_t)id * 8;
  *(s16x8*)&Wh[ce] = hv;
  *(s16x8*)&Wlo[ce] = lv;
}

// ---- zero pad rows 50000..50047 of H panels (kcn=16) -----------------------
// NOTE: H aliases the A0 buffers -> must launch AFTER layer-0 gemm_dual.
__global__ void zero_pad_H(u16* __restrict__ Hh, u16* __restrict__ Hl) {
  int t = blockIdx.x * blockDim.x + threadIdx.x;
  if (t >= 48 * 16) return;
  int m = 16 + (t >> 4), kc = t & 15;
  size_t ce = (((size_t)781 * 16 + kc) * 64 + m) * 8;
  s16x8 z = {0, 0, 0, 0, 0, 0, 0, 0};
  *(s16x8*)&Hh[ce] = z;
  *(s16x8*)&Hl[ce] = z;
}

// ---- dual-output split-bf16 MFMA GEMM: [xl|xr] = A @ [Wl|Wr] + bias --------
__global__ __launch_bounds__(256, 2) void gemm_dual(
    const u16* __restrict__ Ah, const u16* __restrict__ Al,
    const u16* __restrict__ Wh, const u16* __restrict__ Wlo,
    const float* __restrict__ biasl, const float* __restrict__ biasr,
    float* __restrict__ xl, float* __restrict__ xr,
    int Kp, int C, int NL) {
  __shared__ u16 As[2][4][64][8];
  __shared__ u16 Ws[2][4][256][8];
  const int tid = threadIdx.x, wv = tid >> 6, lane = tid & 63;
  const int p = blockIdx.x, n0 = blockIdx.y * 256;
  const int kcn = Kp >> 3, nk = Kp >> 5;
  const size_t abase0 = (size_t)p * kcn * 512;
  const int rsel = lane >> 4, rrow = lane & 15;
  f32x4 z4 = {0.f, 0.f, 0.f, 0.f};
  f32x4 acc[4][4];
#pragma unroll
  for (int a = 0; a < 4; ++a)
#pragma unroll
    for (int b = 0; b < 4; ++b) acc[a][b] = z4;

  for (int s = 0; s < nk; ++s) {
    const size_t abase = abase0 + (size_t)s * 2048;
    for (int q = wv; q < 40; q += 4) {
      const u16* g;
      u16* l;
      if (q < 8) {
        int h = q >> 2, qq = q & 3;
        g = (h ? Al : Ah) + abase + qq * 512;
        l = &As[h][0][0][0] + qq * 512;
      } else {
        int t2 = q - 8, h = t2 >> 4, j = t2 & 15;
        g = (h ? Wlo : Wh) + ((size_t)(s * 4 + (j >> 2)) * WCOLS + n0 + (j & 3) * 64) * 8;
        l = &Ws[h][0][0][0] + j * 512;
      }
      gl_lds16(g + lane * 8, l);
    }
    __syncthreads();
    s16x8 af[4][2], bf[4][2];
#pragma unroll
    for (int mt = 0; mt < 4; ++mt) {
      af[mt][0] = *(const s16x8*)&As[0][rsel][mt * 16 + rrow][0];
      af[mt][1] = *(const s16x8*)&As[1][rsel][mt * 16 + rrow][0];
    }
#pragma unroll
    for (int nt = 0; nt < 4; ++nt) {
      bf[nt][0] = *(const s16x8*)&Ws[0][rsel][wv * 64 + nt * 16 + rrow][0];
      bf[nt][1] = *(const s16x8*)&Ws[1][rsel][wv * 64 + nt * 16 + rrow][0];
    }
#pragma unroll
    for (int mt = 0; mt < 4; ++mt)
#pragma unroll
      for (int nt = 0; nt < 4; ++nt) {
        acc[mt][nt] = __builtin_amdgcn_mfma_f32_16x16x32_bf16(af[mt][1], bf[nt][0], acc[mt][nt], 0, 0, 0);
        acc[mt][nt] = __builtin_amdgcn_mfma_f32_16x16x32_bf16(af[mt][0], bf[nt][1], acc[mt][nt], 0, 0, 0);
        acc[mt][nt] = __builtin_amdgcn_mfma_f32_16x16x32_bf16(af[mt][0], bf[nt][0], acc[mt][nt], 0, 0, 0);
      }
    __syncthreads();
  }
#pragma unroll
  for (int mt = 0; mt < 4; ++mt) {
    int r0 = p * 64 + mt * 16 + rsel * 4;
#pragma unroll
    for (int nt = 0; nt < 4; ++nt) {
      int gc = n0 + wv * 64 + nt * 16 + rrow;
#pragma unroll
      for (int j = 0; j < 4; ++j) {
        int row = r0 + j;
        if (row >= N_NODES) continue;
        float v = acc[mt][nt][j];
        if (gc < NL) {
          if (gc < C) xl[(size_t)row * C + gc] = v + biasl[gc];
        } else {
          int c2 = gc - NL;
          if (c2 >= 0 && c2 < C) xr[(size_t)row * C + c2] = v + biasr[c2];
        }
      }
    }
  }
}

// ---------------- CSR build (once per launch) ---------------------------
__global__ void zero_ints(int* __restrict__ p, int n) {
  int i = blockIdx.x * blockDim.x + threadIdx.x;
  if (i < n) p[i] = 0;
}

__global__ void deg_count(const int* __restrict__ ei, int* __restrict__ deg) {
  int e = blockIdx.x * blockDim.x + threadIdx.x;
  if (e >= E_TOT) return;
  int d = (e < N_EDGES) ? ei[N_EDGES + e] : e - N_EDGES;
  atomicAdd(&deg[d], 1);
}

__global__ void scan1(const int* __restrict__ deg, int* __restrict__ rp,
                      int* __restrict__ bsum) {
  __shared__ int s[256];
  int i = blockIdx.x * 256 + threadIdx.x;
  int v = (i < N_NODES) ? deg[i] : 0;
  s[threadIdx.x] = v;
  __syncthreads();
  for (int off = 1; off < 256; off <<= 1) {
    int t = (threadIdx.x >= off) ? s[threadIdx.x - off] : 0;
    __syncthreads();
    s[threadIdx.x] += t;
    __syncthreads();
  }
  if (i < N_NODES) rp[i] = s[threadIdx.x] - v;
  if (threadIdx.x == 255) bsum[blockIdx.x] = s[255];
}

__global__ void scan2(int* __restrict__ bsum) {
  __shared__ int s[256];
  int v = (threadIdx.x < NB_SCAN) ? bsum[threadIdx.x] : 0;
  s[threadIdx.x] = v;
  __syncthreads();
  for (int off = 1; off < 256; off <<= 1) {
    int t = (threadIdx.x >= off) ? s[threadIdx.x - off] : 0;
    __syncthreads();
    s[threadIdx.x] += t;
    __syncthreads();
  }
  if (threadIdx.x < NB_SCAN) bsum[threadIdx.x] = s[threadIdx.x] - v;
}

__global__ void scan3(int* __restrict__ rp, const int* __restrict__ bsum,
                      int* __restrict__ cursor) {
  int i = blockIdx.x * 256 + threadIdx.x;
  if (i < N_NODES) {
    int v = rp[i] + bsum[blockIdx.x];
    rp[i] = v;
    cursor[i] = v;
  }
  if (i == 0) rp[N_NODES] = E_TOT;
}

__global__ void fill_csr(const int* __restrict__ ei, int* __restrict__ cursor,
                         int* __restrict__ csr_src) {
  int e = blockIdx.x * blockDim.x + threadIdx.x;
  if (e >= E_TOT) return;
  int s, d;
  if (e < N_EDGES) { s = ei[e]; d = ei[N_EDGES + e]; }
  else             { s = d = e - N_EDGES; }
  int pos = atomicAdd(&cursor[d], 1);
  csr_src[pos] = s;
}

// -------- fused GATv2 aggregation: wave per dst node, online softmax ----
template <int C, int OUTB>
__global__ __launch_bounds__(256) void gat_fused(
    const int* __restrict__ rowptr, const int* __restrict__ csr_src,
    const float* __restrict__ xl, const float* __restrict__ xr,
    const float* __restrict__ att, const float* __restrict__ bias,
    float* __restrict__ hout, u16* __restrict__ Hh, u16* __restrict__ Hl) {
  constexpr int NC = (C + 63) / 64;
  int wid = (int)((blockIdx.x * (size_t)blockDim.x + threadIdx.x) >> 6);
  int lane = threadIdx.x & 63;
  if (wid >= N_NODES) return;
  int beg = rowptr[wid], end = rowptr[wid + 1];

  float xri[NC], attc[NC], acc[NC];
#pragma unroll
  for (int j = 0; j < NC; ++j) {
    int c = lane + j * 64;
    bool ok = (c < C);
    xri[j] = ok ? xr[(size_t)wid * C + c] : 0.f;
    attc[j] = ok ? att[c] : 0.f;
    acc[j] = 0.f;
  }
  float mx = -INFINITY, denom = 0.f;
  for (int e = beg; e < end; ++e) {
    int s = csr_src[e];
    float xlv[NC];
    float v = 0.f;
#pragma unroll
    for (int j = 0; j < NC; ++j) {
      int c = lane + j * 64;
      xlv[j] = (c < C) ? xl[(size_t)s * C + c] : 0.f;
      float m = xlv[j] + xri[j];
      float lr = m > 0.f ? m : SLOPE * m;
      v += lr * attc[j];
    }
#pragma unroll
    for (int off = 1; off < 64; off <<= 1) v += __shfl_xor(v, off, 64);
    float nm = fmaxf(mx, v);
    float scale = expf(mx - nm);
    float w = expf(v - nm);
    denom = denom * scale + w;
#pragma unroll
    for (int j = 0; j < NC; ++j) acc[j] = acc[j] * scale + w * xlv[j];
    mx = nm;
  }
  float inv = 1.f / denom;
  if (OUTB) {
    int p = wid >> 6, m = wid & 63;
#pragma unroll
    for (int j = 0; j < NC; ++j) {
      int c = lane + j * 64;
      if (c < C) {
        float v = fmaxf(acc[j] * inv + bias[c], 0.f);
        u16 hb = f2bf(v);
        u16 lb = f2bf(v - bf2f(hb));
        size_t ce = (((size_t)p * (C / 8) + (c >> 3)) * 64 + m) * 8 + (c & 7);
        Hh[ce] = hb;
        Hl[ce] = lb;
      }
    }
  } else {
#pragma unroll
    for (int j = 0; j < NC; ++j) {
      int c = lane + j * 64;
      if (c < C) {
        float v = acc[j] * inv + bias[c];
        hout[(size_t)wid * C + c] = fmaxf(v, 0.f);
      }
    }
  }
}

// ------------- global mean pool (batch sorted) --------------------------
__device__ int lower_bound_dev(const int* a, int n, int v) {
  int lo = 0, hi = n;
  while (lo < hi) { int mid = (lo + hi) >> 1; if (a[mid] < v) lo = mid + 1; else hi = mid; }
  return lo;
}

__global__ void pool_mean(const float* __restrict__ h, const int* __restrict__ batch,
                          float* __restrict__ g, int C) {
  int gi = blockIdx.x;
  int start = lower_bound_dev(batch, N_NODES, gi);
  int end   = lower_bound_dev(batch, N_NODES, gi + 1);
  int cnt = end - start;
  float inv = 1.f / (float)(cnt > 0 ? cnt : 1);
  for (int c = threadIdx.x; c < C; c += blockDim.x) {
    float s = 0.f;
    for (int n = start; n < end; ++n) s += h[(size_t)n * C + c];
    g[(size_t)gi * C + c] = s * inv;
  }
}

// ------------- small per-graph FC ---------------------------------------
__global__ void fc_kernel(const float* __restrict__ g, const float* __restrict__ W,
                          const float* __restrict__ b, float* __restrict__ out,
                          int K, int N, int do_relu) {
  __shared__ float row[304];
  int gi = blockIdx.x;
  for (int k = threadIdx.x; k < K; k += blockDim.x) row[k] = g[(size_t)gi * K + k];
  __syncthreads();
  int c = threadIdx.x;
  if (c >= N) return;
  float s = b[c];
  for (int k = 0; k < K; ++k) s += row[k] * W[(size_t)k * N + c];
  if (do_relu) s = fmaxf(s, 0.f);
  out[(size_t)gi * N + c] = s;
}

extern "C" void kernel_launch(void* const* d_in, const int* in_sizes, int n_in,
                              void* d_out, int out_size, void* d_ws, size_t ws_size,
                              hipStream_t stream) {
  const float* x     = (const float*)d_in[0];
  const int*   ei    = (const int*)d_in[1];
  const int*   batch = (const int*)d_in[2];
  const float* Wl[4], *bl[4], *Wr[4], *br[4], *att[4], *bias[4];
  for (int l = 0; l < 4; ++l) {
    Wl[l]   = (const float*)d_in[3 + l * 6 + 0];
    bl[l]   = (const float*)d_in[3 + l * 6 + 1];
    Wr[l]   = (const float*)d_in[3 + l * 6 + 2];
    br[l]   = (const float*)d_in[3 + l * 6 + 3];
    att[l]  = (const float*)d_in[3 + l * 6 + 4];
    bias[l] = (const float*)d_in[3 + l * 6 + 5];
  }
  const float* fc1_W = (const float*)d_in[27];
  const float* fc1_b = (const float*)d_in[28];
  const float* fc2_W = (const float*)d_in[29];
  const float* fc2_b = (const float*)d_in[30];

  char* wsb = (char*)d_ws;
  size_t off = 0;
  auto alloc = [&](size_t bytes) {
    void* p = (void*)(wsb + off);
    off += (bytes + 63) & ~(size_t)63;
    return p;
  };
  float* xl    = (float*)alloc((size_t)N_NODES * 300 * 4);
  float* xr    = (float*)alloc((size_t)N_NODES * 300 * 4);
  // A0 panels; aliased by H panels (after layer-0 gemm) and hbuf (after layer-3 gemm)
  u16* A0h = (u16*)alloc((size_t)NPANEL * 40 * 512 * 2);   // 32,030,720 B (64B-aligned size)
  u16* A0l = (u16*)alloc((size_t)NPANEL * 40 * 512 * 2);   // contiguous with A0h
  u16* Hh = A0h;                       // needs 12.8 MB  < A0h size
  u16* Hl = A0l;                       // needs 12.8 MB  < A0l size
  float* hbuf = (float*)A0h;           // needs 60 MB    < A0h+A0l combined (64.06 MB)
  float* gpool = (float*)alloc((size_t)N_GRAPHS * 300 * 4);
  float* g1    = (float*)alloc((size_t)N_GRAPHS * 300 * 4);
  const int Kact[4] = {300, 128, 128, 128};
  const int Cdim[4] = {128, 128, 128, 300};
  const int NLv[4]  = {128, 128, 128, 304};
  const int Kpv[4]  = {320, 128, 128, 128};
  u16* Wh[4], *Wlo[4];
  for (int l = 0; l < 4; ++l) {
    int kcn = Kpv[l] >> 3;
    Wh[l]  = (u16*)alloc((size_t)kcn * WCOLS * 8 * 2);
    Wlo[l] = (u16*)alloc((size_t)kcn * WCOLS * 8 * 2);
  }
  int* deg     = (int*)alloc((size_t)N_NODES * 4);
  int* rowptr  = (int*)alloc((size_t)(N_NODES + 1) * 4);
  int* bsum    = (int*)alloc(256 * 4);
  int* cursor  = (int*)alloc((size_t)N_NODES * 4);
  int* csr_src = (int*)alloc((size_t)E_TOT * 4);

  // one-time conversions
  conv_x<<<(NPANEL * 64 * 40 + 255) / 256, 256, 0, stream>>>(x, A0h, A0l);
  for (int l = 0; l < 4; ++l) {
    int kcn = Kpv[l] >> 3;
    conv_w<<<(kcn * WCOLS + 255) / 256, 256, 0, stream>>>(
        Wl[l], Wr[l], Wh[l], Wlo[l], Kact[l], Cdim[l], NLv[l], kcn);
  }

  // CSR build
  zero_ints<<<(N_NODES + 255) / 256, 256, 0, stream>>>(deg, N_NODES);
  deg_count<<<(E_TOT + 255) / 256, 256, 0, stream>>>(ei, deg);
  scan1<<<NB_SCAN, 256, 0, stream>>>(deg, rowptr, bsum);
  scan2<<<1, 256, 0, stream>>>(bsum);
  scan3<<<NB_SCAN, 256, 0, stream>>>(rowptr, bsum, cursor);
  fill_csr<<<(E_TOT + 255) / 256, 256, 0, stream>>>(ei, cursor, csr_src);

  const int nwave_blocks = (N_NODES + 3) / 4;
  for (int l = 0; l < 4; ++l) {
    const u16* Ahs = (l == 0) ? A0h : Hh;
    const u16* Als = (l == 0) ? A0l : Hl;
    int ny = (2 * NLv[l] + 255) / 256;
    dim3 gg(NPANEL, ny);
    gemm_dual<<<gg, 256, 0, stream>>>(Ahs, Als, Wh[l], Wlo[l], bl[l], br[l],
                                      xl, xr, Kpv[l], Cdim[l], NLv[l]);
    if (l == 0) {
      // A0 panels are dead now; H (aliasing A0) pad rows must be zeroed
      zero_pad_H<<<3, 256, 0, stream>>>(Hh, Hl);
    }
    if (l < 3) {
      gat_fused<128, 1><<<nwave_blocks, 256, 0, stream>>>(
          rowptr, csr_src, xl, xr, att[l], bias[l], nullptr, Hh, Hl);
    } else {
      gat_fused<300, 0><<<nwave_blocks, 256, 0, stream>>>(
          rowptr, csr_src, xl, xr, att[l], bias[l], hbuf, nullptr, nullptr);
    }
  }
  pool_mean<<<N_GRAPHS, 256, 0, stream>>>(hbuf, batch, gpool, 300);
  fc_kernel<<<N_GRAPHS, 320, 0, stream>>>(gpool, fc1_W, fc1_b, g1, 300, 300, 1);
  fc_kernel<<<N_GRAPHS, 768, 0, stream>>>(g1, fc2_W, fc2_b, (float*)d_out, 300, 768, 0);
}